// Round 1
// baseline (439.250 us; speedup 1.0000x reference)
//
#include <hip/hip_runtime.h>

// Shapes fixed by the reference setup: B=32, N=64, L=128, D=256.
#define BB 32
#define NN 64
#define LL 128
#define DD 256
#define NBTOT (BB * NN)     // 2048
#define MAX_LEN (NN * LL)   // 8192
#define D4 (DD / 4)         // 64 float4 per row

// ---------------------------------------------------------------------------
// Kernel 1: per-batch inclusive prefix sum of lengths (wave64 scan),
// writes cum[b][n], inv_total[b], lengths_out[b]; zeros encoder_hidden.
// ---------------------------------------------------------------------------
__global__ __launch_bounds__(64) void prefix_kernel(
    const int* __restrict__ lengths,
    int* __restrict__ cum,          // ws: [B][N]
    float* __restrict__ inv_total,  // ws: [B]
    float* __restrict__ lengths_out,// out3: [B]
    float* __restrict__ enc_hidden) // out2: [B][D] (zero-init here)
{
    const int b = blockIdx.x;
    const int lane = threadIdx.x;

    int v = lengths[b * NN + lane];
    // inclusive scan across 64 lanes
    #pragma unroll
    for (int s = 1; s < 64; s <<= 1) {
        int o = __shfl_up(v, s, 64);
        if (lane >= s) v += o;
    }
    cum[b * NN + lane] = v;

    const int total = __shfl(v, 63, 64);
    if (lane == 0) {
        lengths_out[b] = (float)total;
        inv_total[b] = (total > 0) ? (1.0f / (float)total) : 0.0f;
    }
    #pragma unroll
    for (int k = 0; k < DD / 64; ++k)
        enc_hidden[b * DD + k * 64 + lane] = 0.0f;
}

// ---------------------------------------------------------------------------
// Kernel 2: gather-based reconstruction + fused masked mean.
// grid = (MAX_LEN/256, B); block = 256 threads = 4 waves.
// Each block owns batch b and t in [t0, t0+256). Each wave streams 64 rows:
// lanes = float4 channels of D=256 (1 KB coalesced per row, read & write).
// ---------------------------------------------------------------------------
__global__ __launch_bounds__(256) void gather_kernel(
    const float* __restrict__ src,       // [L][NB]
    const float4* __restrict__ mb,       // [L][NB][D] as float4
    const int* __restrict__ recover,     // [NB]
    const int* __restrict__ cum,         // [B][N]
    const float* __restrict__ inv_total, // [B]
    float* __restrict__ src_out,         // [MAX_LEN][B]
    float4* __restrict__ mb_out,         // [MAX_LEN][B][D] as float4
    float* __restrict__ enc_hidden)      // [B][D] (atomic accumulate)
{
    __shared__ int   s_cum[NN];
    __shared__ short s_node[256];
    __shared__ short s_l[256];
    __shared__ float s_accw[4][DD];   // per-wave partial sums

    const int b   = blockIdx.y;
    const int t0  = blockIdx.x * 256;
    const int tid = threadIdx.x;

    if (tid < NN) s_cum[tid] = cum[b * NN + tid];
    __syncthreads();

    const int total = s_cum[NN - 1];
    const int my_t  = t0 + tid;

    // n = number of cum entries <= my_t  (node index for position my_t)
    int n = 0;
    #pragma unroll
    for (int s = 32; s >= 1; s >>= 1) {
        const int cand = n + s;
        if (cand <= NN && s_cum[cand - 1] <= my_t) n = cand;
    }
    const bool valid = (my_t < total);
    const int l = my_t - ((n > 0) ? s_cum[n - 1] : 0);
    s_node[tid] = (short)n;
    s_l[tid]    = (short)l;

    // src_out: 1.0 in padding (reference inits with ones)
    float sv = 1.0f;
    if (valid) sv = src[(size_t)l * NBTOT + recover[b * NN + n]];
    src_out[(size_t)my_t * BB + b] = sv;

    __syncthreads();

    const int wave = tid >> 6;
    const int lane = tid & 63;

    float4 acc = make_float4(0.f, 0.f, 0.f, 0.f);

    #pragma unroll 8
    for (int j = 0; j < 64; ++j) {
        const int idx = wave * 64 + j;
        const int t_j = t0 + idx;
        float4 v = make_float4(0.f, 0.f, 0.f, 0.f);
        if (t_j < total) {                       // wave-uniform branch
            const int n_j = s_node[idx];
            const int l_j = s_l[idx];
            v = mb[((size_t)l_j * NBTOT + (size_t)(b * NN + n_j)) * D4 + lane];
            acc.x += v.x; acc.y += v.y; acc.z += v.z; acc.w += v.w;
        }
        mb_out[((size_t)t_j * BB + b) * D4 + lane] = v;
    }

    // per-wave private LDS rows (no atomics needed), then cross-wave reduce
    s_accw[wave][lane * 4 + 0] = acc.x;
    s_accw[wave][lane * 4 + 1] = acc.y;
    s_accw[wave][lane * 4 + 2] = acc.z;
    s_accw[wave][lane * 4 + 3] = acc.w;
    __syncthreads();

    const float partial = s_accw[0][tid] + s_accw[1][tid]
                        + s_accw[2][tid] + s_accw[3][tid];
    atomicAdd(&enc_hidden[b * DD + tid], partial * inv_total[b]);
}

// ---------------------------------------------------------------------------
extern "C" void kernel_launch(void* const* d_in, const int* in_sizes, int n_in,
                              void* d_out, int out_size, void* d_ws, size_t ws_size,
                              hipStream_t stream) {
    const float* src     = (const float*)d_in[0];   // [L, NB, 1]
    const float* mb      = (const float*)d_in[1];   // [L, NB, D]
    const int*   lengths = (const int*)d_in[2];     // [NB]
    const int*   recover = (const int*)d_in[3];     // [NB]

    float* out = (float*)d_out;
    float* src_out     = out;                                   // 262144
    float* mb_out      = out + (size_t)MAX_LEN * BB;            // 67108864
    float* enc_hidden  = mb_out + (size_t)MAX_LEN * BB * DD;    // 8192
    float* lengths_out = enc_hidden + (size_t)BB * DD;          // 32

    // workspace: cum [B*N] ints, inv_total [B] floats
    int*   cum       = (int*)d_ws;
    float* inv_total = (float*)((char*)d_ws + NBTOT * sizeof(int));

    prefix_kernel<<<BB, 64, 0, stream>>>(lengths, cum, inv_total,
                                         lengths_out, enc_hidden);

    dim3 grid(MAX_LEN / 256, BB);
    gather_kernel<<<grid, 256, 0, stream>>>(src, (const float4*)mb, recover,
                                            cum, inv_total,
                                            src_out, (float4*)mb_out,
                                            enc_hidden);
}

// Round 2
// 424.013 us; speedup vs baseline: 1.0359x; 1.0359x over previous
//
#include <hip/hip_runtime.h>

// Shapes fixed by the reference setup: B=32, N=64, L=128, D=256.
#define BB 32
#define NN 64
#define LL 128
#define DD 256
#define NBTOT (BB * NN)     // 2048
#define MAX_LEN (NN * LL)   // 8192
#define D4 (DD / 4)         // 64 float4 per row

typedef float f32x4 __attribute__((ext_vector_type(4)));

// ---------------------------------------------------------------------------
// Kernel 1: per-batch inclusive prefix sum of lengths (wave64 scan),
// writes cum[b][n], inv_total[b], lengths_out[b]; zeros encoder_hidden.
// ---------------------------------------------------------------------------
__global__ __launch_bounds__(64) void prefix_kernel(
    const int* __restrict__ lengths,
    int* __restrict__ cum,          // ws: [B][N]
    float* __restrict__ inv_total,  // ws: [B]
    float* __restrict__ lengths_out,// out3: [B]
    float* __restrict__ enc_hidden) // out2: [B][D] (zero-init here)
{
    const int b = blockIdx.x;
    const int lane = threadIdx.x;

    int v = lengths[b * NN + lane];
    #pragma unroll
    for (int s = 1; s < 64; s <<= 1) {
        int o = __shfl_up(v, s, 64);
        if (lane >= s) v += o;
    }
    cum[b * NN + lane] = v;

    const int total = __shfl(v, 63, 64);
    if (lane == 0) {
        lengths_out[b] = (float)total;
        inv_total[b] = (total > 0) ? (1.0f / (float)total) : 0.0f;
    }
    #pragma unroll
    for (int k = 0; k < DD / 64; ++k)
        enc_hidden[b * DD + k * 64 + lane] = 0.0f;
}

// ---------------------------------------------------------------------------
// Kernel 2: gather-based reconstruction + fused masked mean.
// grid = (MAX_LEN/256, B); block = 256 threads = 4 waves.
// Each wave streams 64 rows; lanes = float4 channels of D=256 (1 KB
// coalesced per row, read & write). Valid/invalid split keeps the hot loop
// branch-free; row indices come from an intra-wave shuffle (no LDS in loop).
// ---------------------------------------------------------------------------
__global__ __launch_bounds__(256) void gather_kernel(
    const float* __restrict__ src,       // [L][NB]
    const f32x4* __restrict__ mb,        // [L][NB][D] as float4
    const int* __restrict__ recover,     // [NB]
    const int* __restrict__ cum,         // [B][N]
    const float* __restrict__ inv_total, // [B]
    float* __restrict__ src_out,         // [MAX_LEN][B]
    f32x4* __restrict__ mb_out,          // [MAX_LEN][B][D] as float4
    float* __restrict__ enc_hidden)      // [B][D] (atomic accumulate)
{
    __shared__ int   s_cum[NN];
    __shared__ float s_accw[4][DD];      // per-wave partial sums

    const int b    = blockIdx.y;
    const int t0   = blockIdx.x * 256;
    const int tid  = threadIdx.x;
    const int wave = tid >> 6;
    const int lane = tid & 63;

    if (tid < NN) s_cum[tid] = cum[b * NN + tid];
    __syncthreads();

    const int total = s_cum[NN - 1];
    const int my_t  = t0 + tid;

    // n = number of cum entries <= my_t (node index of position my_t)
    int n = 0;
    #pragma unroll
    for (int s = 32; s >= 1; s >>= 1) {
        const int cand = n + s;
        if (cand <= NN && s_cum[cand - 1] <= my_t) n = cand;
    }
    const int l = my_t - ((n > 0) ? s_cum[n - 1] : 0);

    // row index into mb for this thread's output position (garbage if invalid,
    // never consumed in that case)
    const int rowidx = l * NBTOT + b * NN + n;

    // src_out: 1.0 in padding (reference inits with ones). Scalar gather,
    // tiny (1 MB) — stays in L2.
    float sv = 1.0f;
    if (my_t < total) sv = src[(size_t)l * NBTOT + recover[b * NN + n]];
    src_out[(size_t)my_t * BB + b] = sv;

    // ---- streaming loop: wave handles rows t in [wbase, wbase+64) ----
    const int wbase = t0 + wave * 64;
    int nval = total - wbase;
    nval = nval < 0 ? 0 : (nval > 64 ? 64 : nval);

    f32x4 acc = {0.f, 0.f, 0.f, 0.f};

    int j = 0;
    #pragma unroll 4
    for (; j < nval; ++j) {                       // branch-free valid segment
        const int r = __shfl(rowidx, j, 64);      // wave-uniform row index
        f32x4 v = __builtin_nontemporal_load(&mb[(size_t)r * D4 + lane]);
        acc += v;
        __builtin_nontemporal_store(
            v, &mb_out[((size_t)(wbase + j) * BB + b) * D4 + lane]);
    }
    const f32x4 z = {0.f, 0.f, 0.f, 0.f};
    #pragma unroll 8
    for (; j < 64; ++j) {                         // zero-fill tail
        __builtin_nontemporal_store(
            z, &mb_out[((size_t)(wbase + j) * BB + b) * D4 + lane]);
    }

    // per-wave private LDS rows (no atomics), then cross-wave reduce
    s_accw[wave][lane * 4 + 0] = acc.x;
    s_accw[wave][lane * 4 + 1] = acc.y;
    s_accw[wave][lane * 4 + 2] = acc.z;
    s_accw[wave][lane * 4 + 3] = acc.w;
    __syncthreads();

    const float partial = s_accw[0][tid] + s_accw[1][tid]
                        + s_accw[2][tid] + s_accw[3][tid];
    atomicAdd(&enc_hidden[b * DD + tid], partial * inv_total[b]);
}

// ---------------------------------------------------------------------------
extern "C" void kernel_launch(void* const* d_in, const int* in_sizes, int n_in,
                              void* d_out, int out_size, void* d_ws, size_t ws_size,
                              hipStream_t stream) {
    const float* src     = (const float*)d_in[0];   // [L, NB, 1]
    const float* mb      = (const float*)d_in[1];   // [L, NB, D]
    const int*   lengths = (const int*)d_in[2];     // [NB]
    const int*   recover = (const int*)d_in[3];     // [NB]

    float* out = (float*)d_out;
    float* src_out     = out;                                   // 262144
    float* mb_out      = out + (size_t)MAX_LEN * BB;            // 67108864
    float* enc_hidden  = mb_out + (size_t)MAX_LEN * BB * DD;    // 8192
    float* lengths_out = enc_hidden + (size_t)BB * DD;          // 32

    int*   cum       = (int*)d_ws;
    float* inv_total = (float*)((char*)d_ws + NBTOT * sizeof(int));

    prefix_kernel<<<BB, 64, 0, stream>>>(lengths, cum, inv_total,
                                         lengths_out, enc_hidden);

    dim3 grid(MAX_LEN / 256, BB);
    gather_kernel<<<grid, 256, 0, stream>>>(src, (const f32x4*)mb, recover,
                                            cum, inv_total,
                                            src_out, (f32x4*)mb_out,
                                            enc_hidden);
}